// Round 10
// baseline (1550.362 us; speedup 1.0000x reference)
//
#include <hip/hip_runtime.h>
#include <hip/hip_fp16.h>

// GCN, fp16 chain + MFMA GEMMs + bucket-LDS aggregation (no sort, no csr):
//   bucket = dst>>7 (782 buckets of 128 nodes)
//   k_bcount/k_bscan/k_bin: partition edges into bucket runs (src<<7|ldst)
//   k_deg: per-bucket LDS hist -> dis = rsqrt(deg+1)
//   h1' = fp16((x@W1)*dis)  [MFMA 16x16x32_f16, fp32 acc, pre-transposed W]
//   k_agg: block per bucket, fp32 LDS acc[128][66], edge-parallel gather of
//          hp rows + ds_add_f32; epilogue adds self-loop+bias, relu ->
//          a1 fp16 (FUSE=false) or @Wfc+bfc fp32 out (FUSE=true)
// Gather-path is L2-fill bound (~87MB compulsory per R8/R9 model); this round
// removes the counting sort, csr traffic, index-prefetch chain, pad waste,
// and 3 dispatches.

typedef float v2f __attribute__((ext_vector_type(2)));
typedef _Float16 f16x8 __attribute__((ext_vector_type(8)));
typedef float f32x4 __attribute__((ext_vector_type(4)));

// transpose W1,W2 to fp16 [64][KP] once (KP-strided for verbatim LDS copy)
__global__ __launch_bounds__(256) void k_prep(const float* __restrict__ W1,
                                              const float* __restrict__ W2,
                                              _Float16* __restrict__ wt1,
                                              _Float16* __restrict__ wt2) {
    for (int i = threadIdx.x + blockIdx.x * blockDim.x; i < 128 * 64;
         i += gridDim.x * blockDim.x) {
        int k = i >> 6, nn = i & 63;
        wt1[nn * 136 + k] = (_Float16)W1[i];
    }
    for (int i = threadIdx.x + blockIdx.x * blockDim.x; i < 64 * 64;
         i += gridDim.x * blockDim.x) {
        int k = i >> 6, nn = i & 63;
        wt2[nn * 72 + k] = (_Float16)W2[i];
    }
}

__global__ __launch_bounds__(256) void k_bcount(const int* __restrict__ dst, int e,
                                                int* __restrict__ bcnt) {
    __shared__ int lh[1024];
    for (int i = threadIdx.x; i < 1024; i += 256) lh[i] = 0;
    __syncthreads();
    for (int i = blockIdx.x * blockDim.x + threadIdx.x; i < e;
         i += gridDim.x * blockDim.x)
        atomicAdd(&lh[dst[i] >> 7], 1);
    __syncthreads();
    for (int i = threadIdx.x; i < 1024; i += 256)
        if (lh[i]) atomicAdd(&bcnt[i], lh[i]);
}

__global__ __launch_bounds__(1024) void k_bscan(const int* __restrict__ bcnt,
                                                int* __restrict__ bbase,
                                                int* __restrict__ bcur) {
    __shared__ int tmp[1024];
    int t = threadIdx.x;
    int v = bcnt[t];
    tmp[t] = v;
    __syncthreads();
    for (int o = 1; o < 1024; o <<= 1) {
        int x = (t >= o) ? tmp[t - o] : 0;
        __syncthreads();
        tmp[t] += x;
        __syncthreads();
    }
    int ex = tmp[t] - v;
    bbase[t] = ex;
    bcur[t] = ex;
}

// Partition edges into bucket-contiguous runs of packed u32 (src<<7 | ldst).
__global__ __launch_bounds__(256) void k_bin(const int* __restrict__ src,
                                             const int* __restrict__ dst, int e,
                                             int* bcur, unsigned* __restrict__ binned) {
    __shared__ int lh[1024], lbase[1024], lr[1024];
    int t = threadIdx.x;
    for (int i = t; i < 1024; i += 256) { lh[i] = 0; lr[i] = 0; }
    __syncthreads();
    int chunk = (e + gridDim.x - 1) / gridDim.x;
    int lo = blockIdx.x * chunk;
    int hi = min(e, lo + chunk);
    for (int i = lo + t; i < hi; i += 256)
        atomicAdd(&lh[dst[i] >> 7], 1);
    __syncthreads();
    for (int i = t; i < 1024; i += 256)
        lbase[i] = lh[i] ? atomicAdd(&bcur[i], lh[i]) : 0;
    __syncthreads();
    for (int i = lo + t; i < hi; i += 256) {
        int d = dst[i];
        int b = d >> 7;
        int r = atomicAdd(&lr[b], 1);
        binned[lbase[b] + r] = ((unsigned)src[i] << 7) | (unsigned)(d & 127);
    }
}

// One block per bucket: node histogram -> dis = rsqrt(deg+1)
__global__ __launch_bounds__(256) void k_deg(const unsigned* __restrict__ binned,
                                             const int* __restrict__ bbase,
                                             const int* __restrict__ bcnt,
                                             int n, float* __restrict__ dis) {
    __shared__ int nh[128];
    int b = blockIdx.x, t = threadIdx.x;
    if (t < 128) nh[t] = 0;
    __syncthreads();
    int ebase = bbase[b], ecnt = bcnt[b];
    for (int j = t; j < ecnt; j += 256)
        atomicAdd(&nh[binned[ebase + j] & 127u], 1);
    __syncthreads();
    int d = (b << 7) + t;
    if (t < 128 && d < n)
        dis[d] = rsqrtf((float)(nh[t] + 1));   // +1 self-loop
}

// MFMA GEMM: X[n,K] (float or __half) @ Wt (fp16, pre-transposed [64][KP])
//   -> H[row][col] = fp16(acc * dis[row]).  Block: 64 rows, 4 waves.
template<int K, typename TI>
__global__ __launch_bounds__(256) void k_gemm_mfma(const TI* __restrict__ X,
                                                   const _Float16* __restrict__ Wt,
                                                   const float* __restrict__ dis,
                                                   __half* __restrict__ Hh, int n) {
    constexpr int KP = K + 8;
    __shared__ _Float16 As[64 * KP];
    __shared__ _Float16 Bs[64 * KP];

    int t = threadIdx.x;
    _Float16* H = (_Float16*)Hh;

    // stage Wt verbatim (contiguous float4 copy: conflict-free)
    constexpr int NF4 = 64 * KP / 8;
    for (int i = t; i < NF4; i += 256)
        ((float4*)Bs)[i] = ((const float4*)Wt)[i];

    // stage A: each assignment = one row x 8 consecutive k (16B LDS write)
    int row0 = blockIdx.x * 64;
    if (sizeof(TI) == 4) {
        const float* Xf = (const float*)X;
        #pragma unroll
        for (int p = 0; p < 4; ++p) {           // 64 rows x 16 segs
            int gi  = t + p * 256;
            int row = gi >> 4, sg = gi & 15;
            int grow = row0 + row;
            float4 v0 = make_float4(0.f, 0.f, 0.f, 0.f), v1 = v0;
            if (grow < n) {
                v0 = *(const float4*)(Xf + (size_t)grow * K + sg * 8);
                v1 = *(const float4*)(Xf + (size_t)grow * K + sg * 8 + 4);
            }
            union { __half2 h[4]; float4 f; } u;
            u.h[0] = __floats2half2_rn(v0.x, v0.y);
            u.h[1] = __floats2half2_rn(v0.z, v0.w);
            u.h[2] = __floats2half2_rn(v1.x, v1.y);
            u.h[3] = __floats2half2_rn(v1.z, v1.w);
            *(float4*)(As + row * KP + sg * 8) = u.f;
        }
    } else {
        const __half* Xh = (const __half*)X;
        #pragma unroll
        for (int p = 0; p < 2; ++p) {           // 64 rows x 8 segs
            int gi  = t + p * 256;
            int row = gi >> 3, sg = gi & 7;
            int grow = row0 + row;
            float4 v = make_float4(0.f, 0.f, 0.f, 0.f);
            if (grow < n)
                v = *(const float4*)(Xh + (size_t)grow * K + sg * 8);
            *(float4*)(As + row * KP + sg * 8) = v;
        }
    }
    __syncthreads();

    int wv   = t >> 6;
    int lane = t & 63;
    int m    = lane & 15;
    int quad = lane >> 4;
    int r0   = wv * 16;

    f32x4 acc[4] = {};
    const _Float16* Arow = As + (r0 + m) * KP + quad * 8;
    #pragma unroll
    for (int kb = 0; kb < K / 32; ++kb) {
        f16x8 af = *(const f16x8*)(Arow + kb * 32);
        #pragma unroll
        for (int nt = 0; nt < 4; ++nt) {
            f16x8 bf = *(const f16x8*)(Bs + (nt * 16 + m) * KP + quad * 8 + kb * 32);
            acc[nt] = __builtin_amdgcn_mfma_f32_16x16x32_f16(af, bf, acc[nt], 0, 0, 0);
        }
    }

    // D: col = lane&15, row = quad*4 + reg  [m89-verified]
    float dv[4]; int gr[4];
    #pragma unroll
    for (int r = 0; r < 4; ++r) {
        gr[r] = row0 + r0 + quad * 4 + r;
        dv[r] = (gr[r] < n) ? dis[gr[r]] : 0.f;
    }
    #pragma unroll
    for (int nt = 0; nt < 4; ++nt)
        #pragma unroll
        for (int r = 0; r < 4; ++r)
            if (gr[r] < n)
                H[(size_t)gr[r] * 64 + nt * 16 + m] = (_Float16)(acc[nt][r] * dv[r]);
}

// Block per bucket (128 nodes): fp32 LDS accumulate of hp[src] rows over the
// bucket's edges (ds_add_f32; pad 66 breaks the bank coset), then epilogue:
// val = relu(b + dis*(self + acc)). FUSE=false -> fp16 a1; true -> @Wfc+bfc.
template<bool FUSE>
__global__ __launch_bounds__(512) void k_agg(const __half* __restrict__ hp,
                                             const unsigned* __restrict__ binned,
                                             const int* __restrict__ bbase,
                                             const int* __restrict__ bcnt,
                                             const float* __restrict__ dis,
                                             const float* __restrict__ bias,
                                             void* __restrict__ outb,
                                             const float* __restrict__ Wfc,
                                             const float* __restrict__ bfc,
                                             int n) {
    constexpr int AP = 66;                     // pad: bank-coset breaker
    __shared__ float acc[128 * AP];
    int t = threadIdx.x, b = blockIdx.x;
    int node0 = b << 7;

    for (int i = t; i < 64 * AP; i += 512)     // zero via float2 (8448 floats)
        ((float2*)acc)[i] = make_float2(0.f, 0.f);
    __syncthreads();

    int ebase = bbase[b], ecnt = bcnt[b];
    int w = t >> 6, lane = t & 63;
    int g = lane >> 4, m = lane & 15;
    int wslice = (ecnt + 7) >> 3;
    int wstart = w * wslice;
    int wend   = min(wstart + wslice, ecnt);

    for (int base = wstart; base < wend; base += 16) {
        unsigned ew[4]; bool va[4];
        #pragma unroll
        for (int q = 0; q < 4; ++q) {
            int ii = base + q * 4 + g;
            va[q] = ii < wend;
            ew[q] = binned[ebase + (va[q] ? ii : wstart)];
        }
        float2 r[4];
        #pragma unroll
        for (int q = 0; q < 4; ++q) {
            int s = (int)(ew[q] >> 7);
            r[q] = *(const float2*)(hp + (size_t)s * 64 + m * 4);  // 4 halves
        }
        #pragma unroll
        for (int q = 0; q < 4; ++q) {
            if (va[q]) {
                int ld = (int)(ew[q] & 127u);
                const __half2* p2 = (const __half2*)&r[q];
                float2 lo = __half22float2(p2[0]);
                float2 hi = __half22float2(p2[1]);
                float* a = acc + ld * AP + m * 4;
                atomicAdd(a + 0, lo.x);
                atomicAdd(a + 1, lo.y);
                atomicAdd(a + 2, hi.x);
                atomicAdd(a + 3, hi.y);
            }
        }
    }
    __syncthreads();

    // epilogue: 8 threads per node, 8 channels each; two passes of 64 nodes
    int seg = t & 7;
    #pragma unroll
    for (int pass = 0; pass < 2; ++pass) {
        int nl = (t >> 3) + pass * 64;
        int d  = node0 + nl;
        if (d < n) {
            float4 hv = *(const float4*)(hp + (size_t)d * 64 + seg * 8); // 8 halves
            const __half2* ph = (const __half2*)&hv;
            float sf[8];
            #pragma unroll
            for (int c2 = 0; c2 < 4; ++c2) {
                float2 f = __half22float2(ph[c2]);
                sf[c2 * 2] = f.x; sf[c2 * 2 + 1] = f.y;
            }
            float dd = dis[d];
            float vals[8];
            #pragma unroll
            for (int c = 0; c < 8; ++c) {
                float av = acc[nl * AP + seg * 8 + c];
                vals[c] = fmaxf(bias[seg * 8 + c] + dd * (sf[c] + av), 0.f);
            }
            if (!FUSE) {
                union { __half2 h[4]; float4 f; } u;
                #pragma unroll
                for (int c2 = 0; c2 < 4; ++c2)
                    u.h[c2] = __floats2half2_rn(vals[c2 * 2], vals[c2 * 2 + 1]);
                *(float4*)((__half*)outb + (size_t)d * 64 + seg * 8) = u.f;
            } else {
                float4 p = make_float4(0.f, 0.f, 0.f, 0.f);
                #pragma unroll
                for (int c = 0; c < 8; ++c) {
                    float4 wr = ((const float4*)Wfc)[seg * 8 + c];
                    p.x += vals[c] * wr.x; p.y += vals[c] * wr.y;
                    p.z += vals[c] * wr.z; p.w += vals[c] * wr.w;
                }
                #pragma unroll
                for (int q = 1; q <= 4; q <<= 1) {   // 8-lane group reduce
                    p.x += __shfl_xor(p.x, q);
                    p.y += __shfl_xor(p.y, q);
                    p.z += __shfl_xor(p.z, q);
                    p.w += __shfl_xor(p.w, q);
                }
                if (seg == 0) {
                    float4 bf = *(const float4*)bfc;
                    ((float4*)outb)[d] = make_float4(p.x + bf.x, p.y + bf.y,
                                                     p.z + bf.z, p.w + bf.w);
                }
            }
        }
    }
}

static inline size_t align256(size_t x) { return (x + 255) & ~(size_t)255; }

extern "C" void kernel_launch(void* const* d_in, const int* in_sizes, int n_in,
                              void* d_out, int out_size, void* d_ws, size_t ws_size,
                              hipStream_t stream) {
    const float* x   = (const float*)d_in[0];
    const int*   ei  = (const int*)d_in[1];
    const float* W1  = (const float*)d_in[2];
    const float* b1  = (const float*)d_in[3];
    const float* W2  = (const float*)d_in[4];
    const float* b2  = (const float*)d_in[5];
    const float* Wfc = (const float*)d_in[6];
    const float* bfc = (const float*)d_in[7];
    float* out = (float*)d_out;

    int n = in_sizes[0] / 128;   // 100000
    int e = in_sizes[1] / 2;     // 1600000
    const int* src = ei;
    const int* dst = ei + e;

    char* ws = (char*)d_ws;
    size_t p = 0;
    float*    dis    = (float*)   (ws + p); p = align256(p + (size_t)n * 4);
    int*      bcnt   = (int*)     (ws + p); p = align256(p + 1024 * 4);
    int*      bbase  = (int*)     (ws + p); p = align256(p + 1024 * 4);
    int*      bcur   = (int*)     (ws + p); p = align256(p + 1024 * 4);
    _Float16* wt1    = (_Float16*)(ws + p); p = align256(p + 64 * 136 * 2);
    _Float16* wt2    = (_Float16*)(ws + p); p = align256(p + 64 * 72 * 2);
    unsigned* binned = (unsigned*)(ws + p); p = align256(p + (size_t)e * 4);
    __half*   hbuf   = (__half*)  (ws + p); p = align256(p + (size_t)n * 64 * 2);
    __half*   a1h    = (__half*)  (ws + p);           // n*64 fp16

    int gb  = (n + 63) / 64;         // 1563 gemm tiles
    int nbk = (n + 127) / 128;       // 782 buckets

    hipMemsetAsync(bcnt, 0, 1024 * sizeof(int), stream);
    k_prep<<<32, 256, 0, stream>>>(W1, W2, wt1, wt2);
    k_bcount<<<256, 256, 0, stream>>>(dst, e, bcnt);
    k_bscan<<<1, 1024, 0, stream>>>(bcnt, bbase, bcur);
    k_bin<<<128, 256, 0, stream>>>(src, dst, e, bcur, binned);
    k_deg<<<nbk, 256, 0, stream>>>(binned, bbase, bcnt, n, dis);

    // layer 1
    k_gemm_mfma<128, float><<<gb, 256, 0, stream>>>(x, wt1, dis, hbuf, n);
    k_agg<false><<<nbk, 512, 0, stream>>>(hbuf, binned, bbase, bcnt, dis, b1,
                                          a1h, nullptr, nullptr, n);
    // layer 2 + fused final projection
    k_gemm_mfma<64, __half><<<gb, 256, 0, stream>>>(a1h, wt2, dis, hbuf, n);
    k_agg<true><<<nbk, 512, 0, stream>>>(hbuf, binned, bbase, bcnt, dis, b2,
                                         out, Wfc, bfc, n);
}

// Round 11
// 280.645 us; speedup vs baseline: 5.5243x; 5.5243x over previous
//
#include <hip/hip_runtime.h>
#include <hip/hip_fp16.h>

// GCN, fp16 chain + MFMA GEMMs + CSR-sorted gather (R9 structure).
//   bucket = dst>>8 (391 buckets of 256 nodes)
//   k_bcount/k_bscan/k_bin/k_bucket: CSR-by-dst via counting sort
//   h1' = fp16((x@W1)*dis)  [MFMA 16x16x32_f16, fp32 acc, prepped fp16 W]
//   a1  = fp16(relu(b1 + dis*(h1'[d] + sum h1'[src])))   [gather, fp32 acc]
//   h2' = fp16((a1@W2)*dis) -> gather w/ fused @Wfc+bfc (fp32 out)
// R10 lesson (1550us regression): E-scale accumulation through LDS fp32
// atomics serializes (2e5 k-cycles of SQ_LDS_BANK_CONFLICT) — sort-then-sum
// (this structure) is the right pattern. Gather is L2-fill bound at ~57us
// (87MB compulsory per-XCD traffic, R8/R9 model).

typedef float v2f __attribute__((ext_vector_type(2)));
typedef _Float16 f16x8 __attribute__((ext_vector_type(8)));
typedef float f32x4 __attribute__((ext_vector_type(4)));

// transpose W1,W2 to fp16 [64][KP] once (KP-strided for verbatim LDS copy)
__global__ __launch_bounds__(256) void k_prep(const float* __restrict__ W1,
                                              const float* __restrict__ W2,
                                              _Float16* __restrict__ wt1,
                                              _Float16* __restrict__ wt2) {
    for (int i = threadIdx.x + blockIdx.x * blockDim.x; i < 128 * 64;
         i += gridDim.x * blockDim.x) {
        int k = i >> 6, nn = i & 63;
        wt1[nn * 136 + k] = (_Float16)W1[i];
    }
    for (int i = threadIdx.x + blockIdx.x * blockDim.x; i < 64 * 64;
         i += gridDim.x * blockDim.x) {
        int k = i >> 6, nn = i & 63;
        wt2[nn * 72 + k] = (_Float16)W2[i];
    }
}

__global__ __launch_bounds__(256) void k_bcount(const int* __restrict__ dst, int e,
                                                int* __restrict__ bcnt) {
    __shared__ int lh[512];
    for (int i = threadIdx.x; i < 512; i += 256) lh[i] = 0;
    __syncthreads();
    for (int i = blockIdx.x * blockDim.x + threadIdx.x; i < e;
         i += gridDim.x * blockDim.x)
        atomicAdd(&lh[dst[i] >> 8], 1);
    __syncthreads();
    for (int i = threadIdx.x; i < 512; i += 256)
        if (lh[i]) atomicAdd(&bcnt[i], lh[i]);
}

__global__ __launch_bounds__(512) void k_bscan(const int* __restrict__ bcnt,
                                               int* __restrict__ bbase,
                                               int* __restrict__ bcur) {
    __shared__ int tmp[512];
    int t = threadIdx.x;
    int v = bcnt[t];
    tmp[t] = v;
    __syncthreads();
    for (int o = 1; o < 512; o <<= 1) {
        int x = (t >= o) ? tmp[t - o] : 0;
        __syncthreads();
        tmp[t] += x;
        __syncthreads();
    }
    int ex = tmp[t] - v;
    bbase[t] = ex;
    bcur[t] = ex;
}

// Partition edges into bucket-contiguous runs of packed u32 (src<<8 | ldst).
__global__ __launch_bounds__(256) void k_bin(const int* __restrict__ src,
                                             const int* __restrict__ dst, int e,
                                             int* bcur, unsigned* __restrict__ binned) {
    __shared__ int lh[512], lbase[512], lr[512];
    int t = threadIdx.x;
    for (int i = t; i < 512; i += 256) { lh[i] = 0; lr[i] = 0; }
    __syncthreads();
    int chunk = (e + gridDim.x - 1) / gridDim.x;
    int lo = blockIdx.x * chunk;
    int hi = min(e, lo + chunk);
    for (int i = lo + t; i < hi; i += 256)
        atomicAdd(&lh[dst[i] >> 8], 1);
    __syncthreads();
    for (int i = t; i < 512; i += 256)
        lbase[i] = lh[i] ? atomicAdd(&bcur[i], lh[i]) : 0;
    __syncthreads();
    for (int i = lo + t; i < hi; i += 256) {
        int d = dst[i];
        int b = d >> 8;
        int r = atomicAdd(&lr[b], 1);
        binned[lbase[b] + r] = ((unsigned)src[i] << 8) | (unsigned)(d & 255);
    }
}

// One block per bucket: counting sort of <=~4500 edges over 256 local nodes.
__global__ __launch_bounds__(256) void k_bucket(const unsigned* __restrict__ binned,
                                                const int* __restrict__ bbase,
                                                const int* __restrict__ bcnt,
                                                int n, int* __restrict__ offs,
                                                int* __restrict__ cnt,
                                                float* __restrict__ dis,
                                                int* __restrict__ csr) {
    __shared__ int nh[256], nsc[256], nr[256];
    int b = blockIdx.x, t = threadIdx.x;
    int node0 = b << 8;
    int ebase = bbase[b], ecnt = bcnt[b];
    nh[t] = 0; nr[t] = 0;
    __syncthreads();
    for (int j = t; j < ecnt; j += 256)
        atomicAdd(&nh[binned[ebase + j] & 255u], 1);
    __syncthreads();
    int v = nh[t];
    nsc[t] = v;
    __syncthreads();
    for (int o = 1; o < 256; o <<= 1) {
        int x = (t >= o) ? nsc[t - o] : 0;
        __syncthreads();
        nsc[t] += x;
        __syncthreads();
    }
    int ex = nsc[t] - v;
    int d = node0 + t;
    if (d < n) {
        offs[d] = ebase + ex;
        cnt[d]  = v;
        dis[d]  = rsqrtf((float)(v + 1));   // +1 self-loop
    }
    nsc[t] = ex;
    __syncthreads();
    for (int j = t; j < ecnt; j += 256) {
        unsigned ed = binned[ebase + j];
        int ld = ed & 255u;
        int r = atomicAdd(&nr[ld], 1);
        csr[ebase + nsc[ld] + r] = (int)(ed >> 8);
    }
}

// MFMA GEMM: X[n,K] (float or __half) @ Wt (fp16, pre-transposed [64][KP])
//   -> H[row][col] = fp16(acc * dis[row]).  Block: 64 rows, 4 waves.
template<int K, typename TI>
__global__ __launch_bounds__(256) void k_gemm_mfma(const TI* __restrict__ X,
                                                   const _Float16* __restrict__ Wt,
                                                   const float* __restrict__ dis,
                                                   __half* __restrict__ Hh, int n) {
    constexpr int KP = K + 8;
    __shared__ _Float16 As[64 * KP];
    __shared__ _Float16 Bs[64 * KP];

    int t = threadIdx.x;
    _Float16* H = (_Float16*)Hh;

    // stage Wt verbatim (contiguous float4 copy: conflict-free)
    constexpr int NF4 = 64 * KP / 8;
    for (int i = t; i < NF4; i += 256)
        ((float4*)Bs)[i] = ((const float4*)Wt)[i];

    // stage A: each assignment = one row x 8 consecutive k (16B LDS write)
    int row0 = blockIdx.x * 64;
    if (sizeof(TI) == 4) {
        const float* Xf = (const float*)X;
        #pragma unroll
        for (int p = 0; p < 4; ++p) {           // 64 rows x 16 segs
            int gi  = t + p * 256;
            int row = gi >> 4, sg = gi & 15;
            int grow = row0 + row;
            float4 v0 = make_float4(0.f, 0.f, 0.f, 0.f), v1 = v0;
            if (grow < n) {
                v0 = *(const float4*)(Xf + (size_t)grow * K + sg * 8);
                v1 = *(const float4*)(Xf + (size_t)grow * K + sg * 8 + 4);
            }
            union { __half2 h[4]; float4 f; } u;
            u.h[0] = __floats2half2_rn(v0.x, v0.y);
            u.h[1] = __floats2half2_rn(v0.z, v0.w);
            u.h[2] = __floats2half2_rn(v1.x, v1.y);
            u.h[3] = __floats2half2_rn(v1.z, v1.w);
            *(float4*)(As + row * KP + sg * 8) = u.f;
        }
    } else {
        const __half* Xh = (const __half*)X;
        #pragma unroll
        for (int p = 0; p < 2; ++p) {           // 64 rows x 8 segs
            int gi  = t + p * 256;
            int row = gi >> 3, sg = gi & 7;
            int grow = row0 + row;
            float4 v = make_float4(0.f, 0.f, 0.f, 0.f);
            if (grow < n)
                v = *(const float4*)(Xh + (size_t)grow * K + sg * 8);
            *(float4*)(As + row * KP + sg * 8) = v;
        }
    }
    __syncthreads();

    int wv   = t >> 6;
    int lane = t & 63;
    int m    = lane & 15;
    int quad = lane >> 4;
    int r0   = wv * 16;

    f32x4 acc[4] = {};
    const _Float16* Arow = As + (r0 + m) * KP + quad * 8;
    #pragma unroll
    for (int kb = 0; kb < K / 32; ++kb) {
        f16x8 af = *(const f16x8*)(Arow + kb * 32);
        #pragma unroll
        for (int nt = 0; nt < 4; ++nt) {
            f16x8 bf = *(const f16x8*)(Bs + (nt * 16 + m) * KP + quad * 8 + kb * 32);
            acc[nt] = __builtin_amdgcn_mfma_f32_16x16x32_f16(af, bf, acc[nt], 0, 0, 0);
        }
    }

    // D: col = lane&15, row = quad*4 + reg  [m89-verified]
    float dv[4]; int gr[4];
    #pragma unroll
    for (int r = 0; r < 4; ++r) {
        gr[r] = row0 + r0 + quad * 4 + r;
        dv[r] = (gr[r] < n) ? dis[gr[r]] : 0.f;
    }
    #pragma unroll
    for (int nt = 0; nt < 4; ++nt)
        #pragma unroll
        for (int r = 0; r < 4; ++r)
            if (gr[r] < n)
                H[(size_t)gr[r] * 64 + nt * 16 + m] = (_Float16)(acc[nt][r] * dv[r]);
}

__device__ inline void add_row(const __half* __restrict__ hp, int s, int c4,
                               v2f& lo, v2f& hi) {
    float2 raw = *(const float2*)(hp + (size_t)s * 64 + c4);   // 4 halves
    const __half2* p = (const __half2*)&raw;
    float2 l = __half22float2(p[0]);
    float2 h = __half22float2(p[1]);
    lo += (v2f){ l.x, l.y };
    hi += (v2f){ h.x, h.y };
}

// Wave per node: 4 edges x 16 lanes x 4 fp16 channels, fp32 accumulation.
// Indices prefetched + shfl-broadcast in wave-uniform exec (R5 lesson).
// FUSE=false: out is fp16 [n,64] (feeds MFMA GEMM2). FUSE=true: fp32 [n,4].
template<bool FUSE>
__global__ __launch_bounds__(256) void k_gather(const __half* __restrict__ hp,
                                                const int* __restrict__ csr,
                                                const int* __restrict__ off,
                                                const int* __restrict__ cnt,
                                                const float* __restrict__ dis,
                                                const float* __restrict__ bias,
                                                void* __restrict__ outb,
                                                const float* __restrict__ Wfc,
                                                const float* __restrict__ bfc,
                                                int n) {
    int lane = threadIdx.x & 63;
    int wid  = (blockIdx.x * blockDim.x + threadIdx.x) >> 6;
    if (wid >= n) return;                      // wave-uniform (wave per node)
    int d    = wid;
    int esub = lane >> 4;
    int c4   = (lane & 15) * 4;

    int start = off[d], num = cnt[d];
    int idx = (lane < num) ? csr[start + lane] : 0;   // all indices (deg<=64)
    int lim = min(num, 64);

    v2f aL[4] = {}, aH[4] = {};
    if (esub == 0)
        add_row(hp, d, c4, aL[0], aH[0]);      // self-loop

    int j = 0;
    for (; j + 16 <= lim; j += 16) {           // full batches: no clamp needed
        int s0 = __shfl(idx, j + esub);
        int s1 = __shfl(idx, j + 4 + esub);
        int s2 = __shfl(idx, j + 8 + esub);
        int s3 = __shfl(idx, j + 12 + esub);
        add_row(hp, s0, c4, aL[0], aH[0]);
        add_row(hp, s1, c4, aL[1], aH[1]);
        add_row(hp, s2, c4, aL[2], aH[2]);
        add_row(hp, s3, c4, aL[3], aH[3]);
    }
    for (; j < lim; j += 4) {                  // tail: clamp pads to zero row
        int jj = j + esub;                     // jj <= 63 here
        int sr = __shfl(idx, jj);              // uniform exec
        int s  = (jj < lim) ? sr : n;          // zero row at index n
        add_row(hp, s, c4, aL[0], aH[0]);
    }
    for (int j2 = 64; j2 < num; j2 += 4) {     // deg>64: essentially never
        int jj = j2 + esub;
        if (jj < num) {
            int s = csr[start + jj];           // direct load, no shfl
            add_row(hp, s, c4, aL[1], aH[1]);
        }
    }
    v2f sL = (aL[0] + aL[1]) + (aL[2] + aL[3]);
    v2f sH = (aH[0] + aH[1]) + (aH[2] + aH[3]);
    float4 a0 = make_float4(sL.x, sL.y, sH.x, sH.y);
    #pragma unroll
    for (int o = 16; o <= 32; o <<= 1) {
        a0.x += __shfl_xor(a0.x, o);
        a0.y += __shfl_xor(a0.y, o);
        a0.z += __shfl_xor(a0.z, o);
        a0.w += __shfl_xor(a0.w, o);
    }
    float dd = dis[d];
    float4 bb = *(const float4*)(bias + c4);
    float4 o;
    o.x = fmaxf(bb.x + dd * a0.x, 0.f);
    o.y = fmaxf(bb.y + dd * a0.y, 0.f);
    o.z = fmaxf(bb.z + dd * a0.z, 0.f);
    o.w = fmaxf(bb.w + dd * a0.w, 0.f);
    if (!FUSE) {
        if (esub == 0) {
            union { __half2 h[2]; float2 f; } u;
            u.h[0] = __floats2half2_rn(o.x, o.y);
            u.h[1] = __floats2half2_rn(o.z, o.w);
            *(float2*)((__half*)outb + (size_t)d * 64 + c4) = u.f;
        }
    } else {
        const float4* W4 = (const float4*)Wfc;   // row r -> Wfc[r][0..3]
        float4 w0 = W4[c4 + 0], w1 = W4[c4 + 1], w2 = W4[c4 + 2], w3 = W4[c4 + 3];
        float4 p;
        p.x = o.x * w0.x + o.y * w1.x + o.z * w2.x + o.w * w3.x;
        p.y = o.x * w0.y + o.y * w1.y + o.z * w2.y + o.w * w3.y;
        p.z = o.x * w0.z + o.y * w1.z + o.z * w2.z + o.w * w3.z;
        p.w = o.x * w0.w + o.y * w1.w + o.z * w2.w + o.w * w3.w;
        #pragma unroll
        for (int q = 1; q <= 8; q <<= 1) {
            p.x += __shfl_xor(p.x, q);
            p.y += __shfl_xor(p.y, q);
            p.z += __shfl_xor(p.z, q);
            p.w += __shfl_xor(p.w, q);
        }
        if (lane == 0) {
            float4 bf = *(const float4*)bfc;
            float4 r = make_float4(p.x + bf.x, p.y + bf.y, p.z + bf.z, p.w + bf.w);
            ((float4*)outb)[d] = r;
        }
    }
}

static inline size_t align256(size_t x) { return (x + 255) & ~(size_t)255; }

extern "C" void kernel_launch(void* const* d_in, const int* in_sizes, int n_in,
                              void* d_out, int out_size, void* d_ws, size_t ws_size,
                              hipStream_t stream) {
    const float* x   = (const float*)d_in[0];
    const int*   ei  = (const int*)d_in[1];
    const float* W1  = (const float*)d_in[2];
    const float* b1  = (const float*)d_in[3];
    const float* W2  = (const float*)d_in[4];
    const float* b2  = (const float*)d_in[5];
    const float* Wfc = (const float*)d_in[6];
    const float* bfc = (const float*)d_in[7];
    float* out = (float*)d_out;

    int n = in_sizes[0] / 128;   // 100000
    int e = in_sizes[1] / 2;     // 1600000
    const int* src = ei;
    const int* dst = ei + e;

    char* ws = (char*)d_ws;
    size_t p = 0;
    float*    dis    = (float*)   (ws + p); p = align256(p + (size_t)n * 4);
    int*      counts = (int*)     (ws + p); p = align256(p + (size_t)n * 4);
    int*      offs   = (int*)     (ws + p); p = align256(p + (size_t)n * 4);
    int*      bcnt   = (int*)     (ws + p); p = align256(p + 512 * 4);
    int*      bbase  = (int*)     (ws + p); p = align256(p + 512 * 4);
    int*      bcur   = (int*)     (ws + p); p = align256(p + 512 * 4);
    _Float16* wt1    = (_Float16*)(ws + p); p = align256(p + 64 * 136 * 2);
    _Float16* wt2    = (_Float16*)(ws + p); p = align256(p + 64 * 72 * 2);
    int*      csr    = (int*)     (ws + p); p = align256(p + (size_t)e * 4);
    unsigned* binned = (unsigned*)(ws + p); p = align256(p + (size_t)e * 4);
    __half*   hbuf   = (__half*)  (ws + p); p = align256(p + (size_t)(n + 1) * 64 * 2);
    __half*   a1h    = (__half*)  (ws + p);           // n*64 fp16

    int gb  = (n + 63) / 64;         // 1563 gemm tiles
    int nbk = (n + 255) / 256;       // 391 buckets

    // CSR build + zero mask-row for the gather
    hipMemsetAsync(bcnt, 0, 512 * sizeof(int), stream);
    hipMemsetAsync(hbuf + (size_t)n * 64, 0, 64 * sizeof(__half), stream);
    k_prep<<<32, 256, 0, stream>>>(W1, W2, wt1, wt2);
    k_bcount<<<256, 256, 0, stream>>>(dst, e, bcnt);
    k_bscan<<<1, 512, 0, stream>>>(bcnt, bbase, bcur);
    k_bin<<<256, 256, 0, stream>>>(src, dst, e, bcur, binned);
    k_bucket<<<nbk, 256, 0, stream>>>(binned, bbase, bcnt, n, offs, counts, dis, csr);

    // layer 1: h1' (fp16, MFMA) -> a1 (fp16)
    k_gemm_mfma<128, float><<<gb, 256, 0, stream>>>(x, wt1, dis, hbuf, n);
    k_gather<false><<<(n * 64 + 255) / 256, 256, 0, stream>>>(
        hbuf, csr, offs, counts, dis, b1, a1h, nullptr, nullptr, n);

    // layer 2: h2' (fp16, MFMA, reuses hbuf) -> fused final projection
    k_gemm_mfma<64, __half><<<gb, 256, 0, stream>>>(a1h, wt2, dis, hbuf, n);
    k_gather<true><<<(n * 64 + 255) / 256, 256, 0, stream>>>(
        hbuf, csr, offs, counts, dis, b2, out, Wfc, bfc, n);
}

// Round 12
// 269.896 us; speedup vs baseline: 5.7443x; 1.0398x over previous
//
#include <hip/hip_runtime.h>
#include <hip/hip_fp16.h>

// GCN, fp16 chain + MFMA GEMMs + CSR-sorted gather.
//   Fixed-capacity buckets (BCAP slots per 256-node bucket; mean fill 4096,
//   16-sigma safety): k_bin reserves via atomicAdd on zeroed cursors ->
//   NO k_bcount / k_bscan. offs[] carries absolute csr positions so the
//   gather never sees the segmentation.
//   h1' = fp16((x@W1)*dis)  [MFMA 16x16x32_f16, fp32 acc, prepped fp16 W]
//   a1  = fp16(relu(b1 + dis*(h1'[d] + sum h1'[src])))   [gather, fp32 acc]
//   h2' = fp16((a1@W2)*dis) -> gather w/ fused @Wfc+bfc (fp32 out)
// Lessons held: no E-scale LDS atomics (R10: 1550us), shfl only in
// wave-uniform exec (R5), gather at per-request L2-miss floor ~57us
// (R7/R8: MLP x2 and bytes /2 both bounced off it).

#define BCAP 5120   // slots per bucket: mean 4096, sigma 64 -> +16 sigma

typedef float v2f __attribute__((ext_vector_type(2)));
typedef _Float16 f16x8 __attribute__((ext_vector_type(8)));
typedef float f32x4 __attribute__((ext_vector_type(4)));

// one-time: W1,W2 -> fp16 transposed [64][KP]; zero bucket cursors
__global__ __launch_bounds__(256) void k_prep(const float* __restrict__ W1,
                                              const float* __restrict__ W2,
                                              _Float16* __restrict__ wt1,
                                              _Float16* __restrict__ wt2,
                                              int* __restrict__ bcur) {
    int gid = threadIdx.x + blockIdx.x * blockDim.x;   // 8192 threads
    {
        int k = gid >> 6, nn = gid & 63;               // 128*64 elements
        wt1[nn * 136 + k] = (_Float16)W1[gid];
    }
    if (gid < 64 * 64) {
        int k = gid >> 6, nn = gid & 63;
        wt2[nn * 72 + k] = (_Float16)W2[gid];
    }
    if (gid < 512) bcur[gid] = 0;
}

// Partition edges into fixed-capacity bucket segments of packed u32
// (src<<8 | ldst). One global atomic per (block,bucket).
__global__ __launch_bounds__(256) void k_bin(const int* __restrict__ src,
                                             const int* __restrict__ dst, int e,
                                             int* bcur, unsigned* __restrict__ binned) {
    __shared__ int lh[512], lbase[512], lr[512];
    int t = threadIdx.x;
    for (int i = t; i < 512; i += 256) { lh[i] = 0; lr[i] = 0; }
    __syncthreads();
    int chunk = (e + gridDim.x - 1) / gridDim.x;
    int lo = blockIdx.x * chunk;
    int hi = min(e, lo + chunk);
    for (int i = lo + t; i < hi; i += 256)
        atomicAdd(&lh[dst[i] >> 8], 1);
    __syncthreads();
    for (int i = t; i < 512; i += 256)
        lbase[i] = lh[i] ? atomicAdd(&bcur[i], lh[i]) : 0;
    __syncthreads();
    for (int i = lo + t; i < hi; i += 256) {
        int d = dst[i];
        int b = d >> 8;
        int r = atomicAdd(&lr[b], 1);
        binned[(size_t)b * BCAP + lbase[b] + r] =
            ((unsigned)src[i] << 8) | (unsigned)(d & 255);
    }
}

// One block per bucket: counting sort of <=~4600 edges over 256 local nodes.
// bcur now holds the final per-bucket counts.
__global__ __launch_bounds__(256) void k_bucket(const unsigned* __restrict__ binned,
                                                const int* __restrict__ bcur,
                                                int n, int* __restrict__ offs,
                                                int* __restrict__ cnt,
                                                float* __restrict__ dis,
                                                int* __restrict__ csr) {
    __shared__ int nh[256], nsc[256], nr[256];
    int b = blockIdx.x, t = threadIdx.x;
    int node0 = b << 8;
    size_t ebase = (size_t)b * BCAP;
    int ecnt = bcur[b];
    nh[t] = 0; nr[t] = 0;
    __syncthreads();
    for (int j = t; j < ecnt; j += 256)
        atomicAdd(&nh[binned[ebase + j] & 255u], 1);
    __syncthreads();
    int v = nh[t];
    nsc[t] = v;
    __syncthreads();
    for (int o = 1; o < 256; o <<= 1) {
        int x = (t >= o) ? nsc[t - o] : 0;
        __syncthreads();
        nsc[t] += x;
        __syncthreads();
    }
    int ex = nsc[t] - v;
    int d = node0 + t;
    if (d < n) {
        offs[d] = (int)ebase + ex;          // absolute csr position
        cnt[d]  = v;
        dis[d]  = rsqrtf((float)(v + 1));   // +1 self-loop
    }
    nsc[t] = ex;
    __syncthreads();
    for (int j = t; j < ecnt; j += 256) {
        unsigned ed = binned[ebase + j];
        int ld = ed & 255u;
        int r = atomicAdd(&nr[ld], 1);
        csr[ebase + nsc[ld] + r] = (int)(ed >> 8);
    }
}

// MFMA GEMM: X[n,K] (float or __half) @ Wt (fp16, pre-transposed [64][KP])
//   -> H[row][col] = fp16(acc * dis[row]).  Block: 128 rows, 4 waves; wave
// computes 32 rows x 64 cols (B fragments reused across both m-tiles).
// Also writes the zero mask-row at index n (gather padding).
template<int K, typename TI>
__global__ __launch_bounds__(256) void k_gemm_mfma(const TI* __restrict__ X,
                                                   const _Float16* __restrict__ Wt,
                                                   const float* __restrict__ dis,
                                                   __half* __restrict__ Hh, int n) {
    constexpr int KP = K + 8;
    __shared__ _Float16 As[128 * KP];
    __shared__ _Float16 Bs[64 * KP];

    int t = threadIdx.x;
    _Float16* H = (_Float16*)Hh;

    // stage Wt verbatim (contiguous float4 copy: conflict-free)
    constexpr int NF4 = 64 * KP / 8;
    for (int i = t; i < NF4; i += 256)
        ((float4*)Bs)[i] = ((const float4*)Wt)[i];

    // stage A: each assignment = one row x 8 consecutive k (16B LDS write)
    int row0 = blockIdx.x * 128;
    if (sizeof(TI) == 4) {
        const float* Xf = (const float*)X;
        #pragma unroll
        for (int p = 0; p < 8; ++p) {           // 128 rows x 16 segs
            int gi  = t + p * 256;
            int row = gi >> 4, sg = gi & 15;
            int grow = row0 + row;
            float4 v0 = make_float4(0.f, 0.f, 0.f, 0.f), v1 = v0;
            if (grow < n) {
                v0 = *(const float4*)(Xf + (size_t)grow * K + sg * 8);
                v1 = *(const float4*)(Xf + (size_t)grow * K + sg * 8 + 4);
            }
            union { __half2 h[4]; float4 f; } u;
            u.h[0] = __floats2half2_rn(v0.x, v0.y);
            u.h[1] = __floats2half2_rn(v0.z, v0.w);
            u.h[2] = __floats2half2_rn(v1.x, v1.y);
            u.h[3] = __floats2half2_rn(v1.z, v1.w);
            *(float4*)(As + row * KP + sg * 8) = u.f;
        }
    } else {
        const __half* Xh = (const __half*)X;
        #pragma unroll
        for (int p = 0; p < 4; ++p) {           // 128 rows x 8 segs
            int gi  = t + p * 256;
            int row = gi >> 3, sg = gi & 7;
            int grow = row0 + row;
            float4 v = make_float4(0.f, 0.f, 0.f, 0.f);
            if (grow < n)
                v = *(const float4*)(Xh + (size_t)grow * K + sg * 8);
            *(float4*)(As + row * KP + sg * 8) = v;
        }
    }
    __syncthreads();

    int wv   = t >> 6;
    int lane = t & 63;
    int m    = lane & 15;
    int quad = lane >> 4;
    int r0   = wv * 32;

    f32x4 acc[2][4] = {};
    #pragma unroll
    for (int kb = 0; kb < K / 32; ++kb) {
        f16x8 af0 = *(const f16x8*)(As + (r0 + m) * KP + quad * 8 + kb * 32);
        f16x8 af1 = *(const f16x8*)(As + (r0 + 16 + m) * KP + quad * 8 + kb * 32);
        #pragma unroll
        for (int nt = 0; nt < 4; ++nt) {
            f16x8 bf = *(const f16x8*)(Bs + (nt * 16 + m) * KP + quad * 8 + kb * 32);
            acc[0][nt] = __builtin_amdgcn_mfma_f32_16x16x32_f16(af0, bf, acc[0][nt], 0, 0, 0);
            acc[1][nt] = __builtin_amdgcn_mfma_f32_16x16x32_f16(af1, bf, acc[1][nt], 0, 0, 0);
        }
    }

    // D: col = lane&15, row = quad*4 + reg  [m89-verified]
    #pragma unroll
    for (int mt = 0; mt < 2; ++mt) {
        float dv[4]; int gr[4];
        #pragma unroll
        for (int r = 0; r < 4; ++r) {
            gr[r] = row0 + r0 + mt * 16 + quad * 4 + r;
            dv[r] = (gr[r] < n) ? dis[gr[r]] : 0.f;
        }
        #pragma unroll
        for (int nt = 0; nt < 4; ++nt)
            #pragma unroll
            for (int r = 0; r < 4; ++r) {
                if (gr[r] < n)
                    H[(size_t)gr[r] * 64 + nt * 16 + m] =
                        (_Float16)(acc[mt][nt][r] * dv[r]);
                else if (gr[r] == n)   // zero mask-row for the gather
                    H[(size_t)n * 64 + nt * 16 + m] = (_Float16)0.f;
            }
    }
}

__device__ inline void add_row(const __half* __restrict__ hp, int s, int c4,
                               v2f& lo, v2f& hi) {
    float2 raw = *(const float2*)(hp + (size_t)s * 64 + c4);   // 4 halves
    const __half2* p = (const __half2*)&raw;
    float2 l = __half22float2(p[0]);
    float2 h = __half22float2(p[1]);
    lo += (v2f){ l.x, l.y };
    hi += (v2f){ h.x, h.y };
}

// Wave per node: 4 edges x 16 lanes x 4 fp16 channels, fp32 accumulation.
// Indices prefetched + shfl-broadcast in wave-uniform exec (R5 lesson).
// FUSE=false: out is fp16 [n,64] (feeds MFMA GEMM2). FUSE=true: fp32 [n,4].
template<bool FUSE>
__global__ __launch_bounds__(256) void k_gather(const __half* __restrict__ hp,
                                                const int* __restrict__ csr,
                                                const int* __restrict__ off,
                                                const int* __restrict__ cnt,
                                                const float* __restrict__ dis,
                                                const float* __restrict__ bias,
                                                void* __restrict__ outb,
                                                const float* __restrict__ Wfc,
                                                const float* __restrict__ bfc,
                                                int n) {
    int lane = threadIdx.x & 63;
    int wid  = (blockIdx.x * blockDim.x + threadIdx.x) >> 6;
    if (wid >= n) return;                      // wave-uniform (wave per node)
    int d    = wid;
    int esub = lane >> 4;
    int c4   = (lane & 15) * 4;

    int start = off[d], num = cnt[d];
    int idx = (lane < num) ? csr[start + lane] : 0;   // all indices (deg<=64)
    int lim = min(num, 64);

    v2f aL[4] = {}, aH[4] = {};
    if (esub == 0)
        add_row(hp, d, c4, aL[0], aH[0]);      // self-loop

    int j = 0;
    for (; j + 16 <= lim; j += 16) {           // full batches: no clamp needed
        int s0 = __shfl(idx, j + esub);
        int s1 = __shfl(idx, j + 4 + esub);
        int s2 = __shfl(idx, j + 8 + esub);
        int s3 = __shfl(idx, j + 12 + esub);
        add_row(hp, s0, c4, aL[0], aH[0]);
        add_row(hp, s1, c4, aL[1], aH[1]);
        add_row(hp, s2, c4, aL[2], aH[2]);
        add_row(hp, s3, c4, aL[3], aH[3]);
    }
    for (; j < lim; j += 4) {                  // tail: clamp pads to zero row
        int jj = j + esub;                     // jj <= 63 here
        int sr = __shfl(idx, jj);              // uniform exec
        int s  = (jj < lim) ? sr : n;          // zero row at index n
        add_row(hp, s, c4, aL[0], aH[0]);
    }
    for (int j2 = 64; j2 < num; j2 += 4) {     // deg>64: essentially never
        int jj = j2 + esub;
        if (jj < num) {
            int s = csr[start + jj];           // direct load, no shfl
            add_row(hp, s, c4, aL[1], aH[1]);
        }
    }
    v2f sL = (aL[0] + aL[1]) + (aL[2] + aL[3]);
    v2f sH = (aH[0] + aH[1]) + (aH[2] + aH[3]);
    float4 a0 = make_float4(sL.x, sL.y, sH.x, sH.y);
    #pragma unroll
    for (int o = 16; o <= 32; o <<= 1) {
        a0.x += __shfl_xor(a0.x, o);
        a0.y += __shfl_xor(a0.y, o);
        a0.z += __shfl_xor(a0.z, o);
        a0.w += __shfl_xor(a0.w, o);
    }
    float dd = dis[d];
    float4 bb = *(const float4*)(bias + c4);
    float4 o;
    o.x = fmaxf(bb.x + dd * a0.x, 0.f);
    o.y = fmaxf(bb.y + dd * a0.y, 0.f);
    o.z = fmaxf(bb.z + dd * a0.z, 0.f);
    o.w = fmaxf(bb.w + dd * a0.w, 0.f);
    if (!FUSE) {
        if (esub == 0) {
            union { __half2 h[2]; float2 f; } u;
            u.h[0] = __floats2half2_rn(o.x, o.y);
            u.h[1] = __floats2half2_rn(o.z, o.w);
            *(float2*)((__half*)outb + (size_t)d * 64 + c4) = u.f;
        }
    } else {
        const float4* W4 = (const float4*)Wfc;   // row r -> Wfc[r][0..3]
        float4 w0 = W4[c4 + 0], w1 = W4[c4 + 1], w2 = W4[c4 + 2], w3 = W4[c4 + 3];
        float4 p;
        p.x = o.x * w0.x + o.y * w1.x + o.z * w2.x + o.w * w3.x;
        p.y = o.x * w0.y + o.y * w1.y + o.z * w2.y + o.w * w3.y;
        p.z = o.x * w0.z + o.y * w1.z + o.z * w2.z + o.w * w3.z;
        p.w = o.x * w0.w + o.y * w1.w + o.z * w2.w + o.w * w3.w;
        #pragma unroll
        for (int q = 1; q <= 8; q <<= 1) {
            p.x += __shfl_xor(p.x, q);
            p.y += __shfl_xor(p.y, q);
            p.z += __shfl_xor(p.z, q);
            p.w += __shfl_xor(p.w, q);
        }
        if (lane == 0) {
            float4 bf = *(const float4*)bfc;
            float4 r = make_float4(p.x + bf.x, p.y + bf.y, p.z + bf.z, p.w + bf.w);
            ((float4*)outb)[d] = r;
        }
    }
}

static inline size_t align256(size_t x) { return (x + 255) & ~(size_t)255; }

extern "C" void kernel_launch(void* const* d_in, const int* in_sizes, int n_in,
                              void* d_out, int out_size, void* d_ws, size_t ws_size,
                              hipStream_t stream) {
    const float* x   = (const float*)d_in[0];
    const int*   ei  = (const int*)d_in[1];
    const float* W1  = (const float*)d_in[2];
    const float* b1  = (const float*)d_in[3];
    const float* W2  = (const float*)d_in[4];
    const float* b2  = (const float*)d_in[5];
    const float* Wfc = (const float*)d_in[6];
    const float* bfc = (const float*)d_in[7];
    float* out = (float*)d_out;

    int n = in_sizes[0] / 128;   // 100000
    int e = in_sizes[1] / 2;     // 1600000
    const int* src = ei;
    const int* dst = ei + e;

    char* ws = (char*)d_ws;
    size_t p = 0;
    float*    dis    = (float*)   (ws + p); p = align256(p + (size_t)n * 4);
    int*      counts = (int*)     (ws + p); p = align256(p + (size_t)n * 4);
    int*      offs   = (int*)     (ws + p); p = align256(p + (size_t)n * 4);
    int*      bcur   = (int*)     (ws + p); p = align256(p + 512 * 4);
    _Float16* wt1    = (_Float16*)(ws + p); p = align256(p + 64 * 136 * 2);
    _Float16* wt2    = (_Float16*)(ws + p); p = align256(p + 64 * 72 * 2);
    int*      csr    = (int*)     (ws + p); p = align256(p + (size_t)512 * BCAP * 4);
    unsigned* binned = (unsigned*)(ws + p); p = align256(p + (size_t)512 * BCAP * 4);
    __half*   hbuf   = (__half*)  (ws + p); p = align256(p + (size_t)(n + 1) * 64 * 2);
    __half*   a1h    = (__half*)  (ws + p);           // n*64 fp16

    int gb  = (n + 127) / 128;       // 782 gemm tiles (last covers row n)
    int nbk = (n + 255) / 256;       // 391 buckets

    // prep (W transposes + cursor zero) + CSR build (fixed-capacity buckets)
    k_prep<<<32, 256, 0, stream>>>(W1, W2, wt1, wt2, bcur);
    k_bin<<<256, 256, 0, stream>>>(src, dst, e, bcur, binned);
    k_bucket<<<nbk, 256, 0, stream>>>(binned, bcur, n, offs, counts, dis, csr);

    // layer 1: h1' (fp16, MFMA) -> a1 (fp16)
    k_gemm_mfma<128, float><<<gb, 256, 0, stream>>>(x, wt1, dis, hbuf, n);
    k_gather<false><<<(n * 64 + 255) / 256, 256, 0, stream>>>(
        hbuf, csr, offs, counts, dis, b1, a1h, nullptr, nullptr, n);

    // layer 2: h2' (fp16, MFMA, reuses hbuf) -> fused final projection
    k_gemm_mfma<64, __half><<<gb, 256, 0, stream>>>(a1h, wt2, dis, hbuf, n);
    k_gather<true><<<(n * 64 + 255) / 256, 256, 0, stream>>>(
        hbuf, csr, offs, counts, dis, b2, out, Wfc, bfc, n);
}

// Round 13
// 264.861 us; speedup vs baseline: 5.8535x; 1.0190x over previous
//
#include <hip/hip_runtime.h>
#include <hip/hip_fp16.h>

// GCN, fp16 chain + MFMA GEMMs + CSR-sorted gather.
//   Fixed-capacity buckets (BCAP slots per 256-node bucket, +16 sigma).
//   k_bin: single-pass (edges cached in LDS), 512 blocks.
//   k_bucket: single-pass counting sort (bucket run cached in LDS).
//   h1' = fp16((x@W1)*dis)  [MFMA 16x16x32_f16, fp32 acc, prepped fp16 W]
//   a1  = fp16(relu(b1 + dis*(h1'[d] + sum h1'[src])))   [gather, fp32 acc]
//   h2' = fp16((a1@W2)*dis) -> gather w/ fused @Wfc+bfc (fp32 out)
// Lessons held: no E-scale LDS fp32 atomics (R10: 1550us), shfl only in
// wave-uniform exec (R5), gather at per-request L2-miss floor ~57us
// (R7/R8/R9: MLP x2, bytes /2, structure swap all bounced off it).

#define BCAP 5120    // slots per bucket: mean 4096, sigma 64 -> +16 sigma
#define BINB 512     // k_bin grid
#define CHUNK 3200   // >= ceil(E / BINB) = 3125

typedef float v2f __attribute__((ext_vector_type(2)));
typedef _Float16 f16x8 __attribute__((ext_vector_type(8)));
typedef float f32x4 __attribute__((ext_vector_type(4)));

// one-time: W1,W2 -> fp16 transposed [64][KP]; zero bucket cursors
__global__ __launch_bounds__(256) void k_prep(const float* __restrict__ W1,
                                              const float* __restrict__ W2,
                                              _Float16* __restrict__ wt1,
                                              _Float16* __restrict__ wt2,
                                              int* __restrict__ bcur) {
    int gid = threadIdx.x + blockIdx.x * blockDim.x;   // 8192 threads
    {
        int k = gid >> 6, nn = gid & 63;               // 128*64 elements
        wt1[nn * 136 + k] = (_Float16)W1[gid];
    }
    if (gid < 64 * 64) {
        int k = gid >> 6, nn = gid & 63;
        wt2[nn * 72 + k] = (_Float16)W2[gid];
    }
    if (gid < 512) bcur[gid] = 0;
}

// Partition edges into fixed-capacity bucket segments of packed u32
// (src<<8 | ldst). Single global read: edges cached in LDS between the
// histogram pass and the ranked scatter. One global atomic per (block,bucket).
__global__ __launch_bounds__(256) void k_bin(const int* __restrict__ src,
                                             const int* __restrict__ dst, int e,
                                             int* bcur, unsigned* __restrict__ binned) {
    __shared__ unsigned ec[CHUNK];          // packed src<<8|ldst
    __shared__ unsigned short eb[CHUNK];    // bucket id
    __shared__ int lh[512], lbase[512], lr[512];
    int t = threadIdx.x;
    for (int i = t; i < 512; i += 256) { lh[i] = 0; lr[i] = 0; }
    __syncthreads();
    int chunk = (e + gridDim.x - 1) / gridDim.x;   // 3125 <= CHUNK
    int lo = blockIdx.x * chunk;
    int hi = min(e, lo + chunk);
    for (int i = lo + t; i < hi; i += 256) {
        int d = dst[i];
        int b = d >> 8;
        ec[i - lo] = ((unsigned)src[i] << 8) | (unsigned)(d & 255);
        eb[i - lo] = (unsigned short)b;
        atomicAdd(&lh[b], 1);
    }
    __syncthreads();
    for (int i = t; i < 512; i += 256)
        lbase[i] = lh[i] ? atomicAdd(&bcur[i], lh[i]) : 0;
    __syncthreads();
    int cnt = hi - lo;
    for (int i = t; i < cnt; i += 256) {
        int b = eb[i];
        int r = lbase[b] + atomicAdd(&lr[b], 1);
        if (r < BCAP)                       // overflow guard (never at 16 sigma)
            binned[(size_t)b * BCAP + r] = ec[i];
    }
}

// One block per bucket: counting sort of <=BCAP edges over 256 local nodes.
// Bucket run staged in LDS on the histogram pass (single global read).
// bcur holds the final per-bucket counts.
__global__ __launch_bounds__(256) void k_bucket(const unsigned* __restrict__ binned,
                                                const int* __restrict__ bcur,
                                                int n, int* __restrict__ offs,
                                                int* __restrict__ cnt,
                                                float* __restrict__ dis,
                                                int* __restrict__ csr) {
    __shared__ unsigned ec[BCAP];
    __shared__ int nh[256], nsc[256], nr[256];
    int b = blockIdx.x, t = threadIdx.x;
    int node0 = b << 8;
    size_t ebase = (size_t)b * BCAP;
    int ecnt = min(bcur[b], BCAP);
    nh[t] = 0; nr[t] = 0;
    __syncthreads();
    for (int j = t; j < ecnt; j += 256) {
        unsigned ed = binned[ebase + j];
        ec[j] = ed;
        atomicAdd(&nh[ed & 255u], 1);
    }
    __syncthreads();
    int v = nh[t];
    nsc[t] = v;
    __syncthreads();
    for (int o = 1; o < 256; o <<= 1) {
        int x = (t >= o) ? nsc[t - o] : 0;
        __syncthreads();
        nsc[t] += x;
        __syncthreads();
    }
    int ex = nsc[t] - v;
    int d = node0 + t;
    if (d < n) {
        offs[d] = (int)ebase + ex;          // absolute csr position
        cnt[d]  = v;
        dis[d]  = rsqrtf((float)(v + 1));   // +1 self-loop
    }
    nsc[t] = ex;
    __syncthreads();
    for (int j = t; j < ecnt; j += 256) {
        unsigned ed = ec[j];
        int ld = ed & 255u;
        int r = atomicAdd(&nr[ld], 1);
        csr[ebase + nsc[ld] + r] = (int)(ed >> 8);
    }
}

// MFMA GEMM: X[n,K] (float or __half) @ Wt (fp16, pre-transposed [64][KP])
//   -> H[row][col] = fp16(acc * dis[row]).  Block: 128 rows, 4 waves; wave
// computes 32 rows x 64 cols (B fragments reused across both m-tiles).
// Also writes the zero mask-row at index n (gather padding).
template<int K, typename TI>
__global__ __launch_bounds__(256) void k_gemm_mfma(const TI* __restrict__ X,
                                                   const _Float16* __restrict__ Wt,
                                                   const float* __restrict__ dis,
                                                   __half* __restrict__ Hh, int n) {
    constexpr int KP = K + 8;
    __shared__ _Float16 As[128 * KP];
    __shared__ _Float16 Bs[64 * KP];

    int t = threadIdx.x;
    _Float16* H = (_Float16*)Hh;

    // stage Wt verbatim (contiguous float4 copy: conflict-free)
    constexpr int NF4 = 64 * KP / 8;
    for (int i = t; i < NF4; i += 256)
        ((float4*)Bs)[i] = ((const float4*)Wt)[i];

    // stage A: each assignment = one row x 8 consecutive k (16B LDS write)
    int row0 = blockIdx.x * 128;
    if (sizeof(TI) == 4) {
        const float* Xf = (const float*)X;
        #pragma unroll
        for (int p = 0; p < 8; ++p) {           // 128 rows x 16 segs
            int gi  = t + p * 256;
            int row = gi >> 4, sg = gi & 15;
            int grow = row0 + row;
            float4 v0 = make_float4(0.f, 0.f, 0.f, 0.f), v1 = v0;
            if (grow < n) {
                v0 = *(const float4*)(Xf + (size_t)grow * K + sg * 8);
                v1 = *(const float4*)(Xf + (size_t)grow * K + sg * 8 + 4);
            }
            union { __half2 h[4]; float4 f; } u;
            u.h[0] = __floats2half2_rn(v0.x, v0.y);
            u.h[1] = __floats2half2_rn(v0.z, v0.w);
            u.h[2] = __floats2half2_rn(v1.x, v1.y);
            u.h[3] = __floats2half2_rn(v1.z, v1.w);
            *(float4*)(As + row * KP + sg * 8) = u.f;
        }
    } else {
        const __half* Xh = (const __half*)X;
        #pragma unroll
        for (int p = 0; p < 4; ++p) {           // 128 rows x 8 segs
            int gi  = t + p * 256;
            int row = gi >> 3, sg = gi & 7;
            int grow = row0 + row;
            float4 v = make_float4(0.f, 0.f, 0.f, 0.f);
            if (grow < n)
                v = *(const float4*)(Xh + (size_t)grow * K + sg * 8);
            *(float4*)(As + row * KP + sg * 8) = v;
        }
    }
    __syncthreads();

    int wv   = t >> 6;
    int lane = t & 63;
    int m    = lane & 15;
    int quad = lane >> 4;
    int r0   = wv * 32;

    f32x4 acc[2][4] = {};
    #pragma unroll
    for (int kb = 0; kb < K / 32; ++kb) {
        f16x8 af0 = *(const f16x8*)(As + (r0 + m) * KP + quad * 8 + kb * 32);
        f16x8 af1 = *(const f16x8*)(As + (r0 + 16 + m) * KP + quad * 8 + kb * 32);
        #pragma unroll
        for (int nt = 0; nt < 4; ++nt) {
            f16x8 bf = *(const f16x8*)(Bs + (nt * 16 + m) * KP + quad * 8 + kb * 32);
            acc[0][nt] = __builtin_amdgcn_mfma_f32_16x16x32_f16(af0, bf, acc[0][nt], 0, 0, 0);
            acc[1][nt] = __builtin_amdgcn_mfma_f32_16x16x32_f16(af1, bf, acc[1][nt], 0, 0, 0);
        }
    }

    // D: col = lane&15, row = quad*4 + reg  [m89-verified]
    #pragma unroll
    for (int mt = 0; mt < 2; ++mt) {
        float dv[4]; int gr[4];
        #pragma unroll
        for (int r = 0; r < 4; ++r) {
            gr[r] = row0 + r0 + mt * 16 + quad * 4 + r;
            dv[r] = (gr[r] < n) ? dis[gr[r]] : 0.f;
        }
        #pragma unroll
        for (int nt = 0; nt < 4; ++nt)
            #pragma unroll
            for (int r = 0; r < 4; ++r) {
                if (gr[r] < n)
                    H[(size_t)gr[r] * 64 + nt * 16 + m] =
                        (_Float16)(acc[mt][nt][r] * dv[r]);
                else if (gr[r] == n)   // zero mask-row for the gather
                    H[(size_t)n * 64 + nt * 16 + m] = (_Float16)0.f;
            }
    }
}

__device__ inline void add_row(const __half* __restrict__ hp, int s, int c4,
                               v2f& lo, v2f& hi) {
    float2 raw = *(const float2*)(hp + (size_t)s * 64 + c4);   // 4 halves
    const __half2* p = (const __half2*)&raw;
    float2 l = __half22float2(p[0]);
    float2 h = __half22float2(p[1]);
    lo += (v2f){ l.x, l.y };
    hi += (v2f){ h.x, h.y };
}

// Wave per node: 4 edges x 16 lanes x 4 fp16 channels, fp32 accumulation.
// Indices prefetched + shfl-broadcast in wave-uniform exec (R5 lesson).
// FUSE=false: out is fp16 [n,64] (feeds MFMA GEMM2). FUSE=true: fp32 [n,4].
template<bool FUSE>
__global__ __launch_bounds__(256) void k_gather(const __half* __restrict__ hp,
                                                const int* __restrict__ csr,
                                                const int* __restrict__ off,
                                                const int* __restrict__ cnt,
                                                const float* __restrict__ dis,
                                                const float* __restrict__ bias,
                                                void* __restrict__ outb,
                                                const float* __restrict__ Wfc,
                                                const float* __restrict__ bfc,
                                                int n) {
    int lane = threadIdx.x & 63;
    int wid  = (blockIdx.x * blockDim.x + threadIdx.x) >> 6;
    if (wid >= n) return;                      // wave-uniform (wave per node)
    int d    = wid;
    int esub = lane >> 4;
    int c4   = (lane & 15) * 4;

    int start = off[d], num = cnt[d];
    int idx = (lane < num) ? csr[start + lane] : 0;   // all indices (deg<=64)
    int lim = min(num, 64);

    v2f aL[4] = {}, aH[4] = {};
    if (esub == 0)
        add_row(hp, d, c4, aL[0], aH[0]);      // self-loop

    int j = 0;
    for (; j + 16 <= lim; j += 16) {           // full batches: no clamp needed
        int s0 = __shfl(idx, j + esub);
        int s1 = __shfl(idx, j + 4 + esub);
        int s2 = __shfl(idx, j + 8 + esub);
        int s3 = __shfl(idx, j + 12 + esub);
        add_row(hp, s0, c4, aL[0], aH[0]);
        add_row(hp, s1, c4, aL[1], aH[1]);
        add_row(hp, s2, c4, aL[2], aH[2]);
        add_row(hp, s3, c4, aL[3], aH[3]);
    }
    for (; j < lim; j += 4) {                  // tail: clamp pads to zero row
        int jj = j + esub;                     // jj <= 63 here
        int sr = __shfl(idx, jj);              // uniform exec
        int s  = (jj < lim) ? sr : n;          // zero row at index n
        add_row(hp, s, c4, aL[0], aH[0]);
    }
    for (int j2 = 64; j2 < num; j2 += 4) {     // deg>64: essentially never
        int jj = j2 + esub;
        if (jj < num) {
            int s = csr[start + jj];           // direct load, no shfl
            add_row(hp, s, c4, aL[1], aH[1]);
        }
    }
    v2f sL = (aL[0] + aL[1]) + (aL[2] + aL[3]);
    v2f sH = (aH[0] + aH[1]) + (aH[2] + aH[3]);
    float4 a0 = make_float4(sL.x, sL.y, sH.x, sH.y);
    #pragma unroll
    for (int o = 16; o <= 32; o <<= 1) {
        a0.x += __shfl_xor(a0.x, o);
        a0.y += __shfl_xor(a0.y, o);
        a0.z += __shfl_xor(a0.z, o);
        a0.w += __shfl_xor(a0.w, o);
    }
    float dd = dis[d];
    float4 bb = *(const float4*)(bias + c4);
    float4 o;
    o.x = fmaxf(bb.x + dd * a0.x, 0.f);
    o.y = fmaxf(bb.y + dd * a0.y, 0.f);
    o.z = fmaxf(bb.z + dd * a0.z, 0.f);
    o.w = fmaxf(bb.w + dd * a0.w, 0.f);
    if (!FUSE) {
        if (esub == 0) {
            union { __half2 h[2]; float2 f; } u;
            u.h[0] = __floats2half2_rn(o.x, o.y);
            u.h[1] = __floats2half2_rn(o.z, o.w);
            *(float2*)((__half*)outb + (size_t)d * 64 + c4) = u.f;
        }
    } else {
        const float4* W4 = (const float4*)Wfc;   // row r -> Wfc[r][0..3]
        float4 w0 = W4[c4 + 0], w1 = W4[c4 + 1], w2 = W4[c4 + 2], w3 = W4[c4 + 3];
        float4 p;
        p.x = o.x * w0.x + o.y * w1.x + o.z * w2.x + o.w * w3.x;
        p.y = o.x * w0.y + o.y * w1.y + o.z * w2.y + o.w * w3.y;
        p.z = o.x * w0.z + o.y * w1.z + o.z * w2.z + o.w * w3.z;
        p.w = o.x * w0.w + o.y * w1.w + o.z * w2.w + o.w * w3.w;
        #pragma unroll
        for (int q = 1; q <= 8; q <<= 1) {
            p.x += __shfl_xor(p.x, q);
            p.y += __shfl_xor(p.y, q);
            p.z += __shfl_xor(p.z, q);
            p.w += __shfl_xor(p.w, q);
        }
        if (lane == 0) {
            float4 bf = *(const float4*)bfc;
            float4 r = make_float4(p.x + bf.x, p.y + bf.y, p.z + bf.z, p.w + bf.w);
            ((float4*)outb)[d] = r;
        }
    }
}

static inline size_t align256(size_t x) { return (x + 255) & ~(size_t)255; }

extern "C" void kernel_launch(void* const* d_in, const int* in_sizes, int n_in,
                              void* d_out, int out_size, void* d_ws, size_t ws_size,
                              hipStream_t stream) {
    const float* x   = (const float*)d_in[0];
    const int*   ei  = (const int*)d_in[1];
    const float* W1  = (const float*)d_in[2];
    const float* b1  = (const float*)d_in[3];
    const float* W2  = (const float*)d_in[4];
    const float* b2  = (const float*)d_in[5];
    const float* Wfc = (const float*)d_in[6];
    const float* bfc = (const float*)d_in[7];
    float* out = (float*)d_out;

    int n = in_sizes[0] / 128;   // 100000
    int e = in_sizes[1] / 2;     // 1600000
    const int* src = ei;
    const int* dst = ei + e;

    char* ws = (char*)d_ws;
    size_t p = 0;
    float*    dis    = (float*)   (ws + p); p = align256(p + (size_t)n * 4);
    int*      counts = (int*)     (ws + p); p = align256(p + (size_t)n * 4);
    int*      offs   = (int*)     (ws + p); p = align256(p + (size_t)n * 4);
    int*      bcur   = (int*)     (ws + p); p = align256(p + 512 * 4);
    _Float16* wt1    = (_Float16*)(ws + p); p = align256(p + 64 * 136 * 2);
    _Float16* wt2    = (_Float16*)(ws + p); p = align256(p + 64 * 72 * 2);
    int*      csr    = (int*)     (ws + p); p = align256(p + (size_t)512 * BCAP * 4);
    unsigned* binned = (unsigned*)(ws + p); p = align256(p + (size_t)512 * BCAP * 4);
    __half*   hbuf   = (__half*)  (ws + p); p = align256(p + (size_t)(n + 1) * 64 * 2);
    __half*   a1h    = (__half*)  (ws + p);           // n*64 fp16

    int gb  = (n + 127) / 128;       // 782 gemm tiles (last covers row n)
    int nbk = (n + 255) / 256;       // 391 buckets

    // prep (W transposes + cursor zero) + CSR build (fixed-capacity buckets)
    k_prep<<<32, 256, 0, stream>>>(W1, W2, wt1, wt2, bcur);
    k_bin<<<BINB, 256, 0, stream>>>(src, dst, e, bcur, binned);
    k_bucket<<<nbk, 256, 0, stream>>>(binned, bcur, n, offs, counts, dis, csr);

    // layer 1: h1' (fp16, MFMA) -> a1 (fp16)
    k_gemm_mfma<128, float><<<gb, 256, 0, stream>>>(x, wt1, dis, hbuf, n);
    k_gather<false><<<(n * 64 + 255) / 256, 256, 0, stream>>>(
        hbuf, csr, offs, counts, dis, b1, a1h, nullptr, nullptr, n);

    // layer 2: h2' (fp16, MFMA, reuses hbuf) -> fused final projection
    k_gemm_mfma<64, __half><<<gb, 256, 0, stream>>>(a1h, wt2, dis, hbuf, n);
    k_gather<true><<<(n * 64 + 255) / 256, 256, 0, stream>>>(
        hbuf, csr, offs, counts, dis, b2, out, Wfc, bfc, n);
}